// Round 5
// baseline (4794.467 us; speedup 1.0000x reference)
//
#include <hip/hip_runtime.h>
#include <hip/hip_fp16.h>

typedef _Float16 h16;
typedef _Float16 v8h  __attribute__((ext_vector_type(8)));
typedef float    v4f  __attribute__((ext_vector_type(4)));
typedef unsigned int v4u __attribute__((ext_vector_type(4)));

// all-16-producers-done pattern: 16 bytes each == 1
#define FPAT 0x0101010101010101ull

struct PParams {
  const float* x;                 // [64][512][256] fp32
  const float* Wih[4];            // [2048][KIN]
  const float* Whh[4];            // [2048][512]
  const float* bih[4];
  const float* bhh[4];
  h16* s[4];                      // streams: l=0..2 [512][64][512], l=3 [2][64][512]
  unsigned char* flags;           // [16 g][512 t][16 wg] L3 bytes (always published)
  unsigned char* flagL2;          // [16 g][512 t][16 wg] intra-XCD bytes (mode only)
  unsigned char* xcctab;          // [16 g][16 wg] placement handshake
  h16* hbuf;                      // [16 g][2][16][512] XCD-local h ping-pong
};

__device__ inline float fsigmoid(float x){
  float e = __builtin_amdgcn_exp2f(-1.4426950408889634f * __builtin_fabsf(x));
  float r = __builtin_amdgcn_rcpf(1.0f + e);
  return x >= 0.f ? r : e * r;
}
__device__ inline float ftanhf(float x){
  float e = __builtin_amdgcn_exp2f(-2.8853900817779268f * __builtin_fabsf(x));
  float t = (1.0f - e) * __builtin_amdgcn_rcpf(1.0f + e);
  return x >= 0.f ? t : -t;
}

// ---- L3-scope (agent) ops: cross-XCD visibility, bypass per-XCD L2. Proven
// in rounds 0/4.
__device__ inline unsigned long long cload64(const void* p){
  return __hip_atomic_load((const unsigned long long*)p, __ATOMIC_RELAXED,
                           __HIP_MEMORY_SCOPE_AGENT);
}
__device__ inline void cstore32(void* p, unsigned int v){
  __hip_atomic_store((unsigned int*)p, v, __ATOMIC_RELAXED, __HIP_MEMORY_SCOPE_AGENT);
}
__device__ inline void cstore8(void* p, unsigned char v){
  __hip_atomic_store((unsigned char*)p, v, __ATOMIC_RELAXED, __HIP_MEMORY_SCOPE_AGENT);
}

__device__ inline void wait_flag16(const unsigned long long* f){
  int it = 0;
  while (true){
    unsigned long long a = cload64(f);
    unsigned long long b = cload64(f + 1);
    if ((a & b) == FPAT) break;
    __builtin_amdgcn_s_sleep(1);
    if (++it > (1 << 21)) break;   // safety valve: never hang the harness
  }
}

// ---- L2-scope (intra-XCD) ops: sc0 only -> served by the XCD's coherent L2.
// Every load asm folds its own s_waitcnt so the compiler can never touch a
// not-yet-written destination register (round-3 lesson).
__device__ inline bool poll_l2_16(const unsigned char* f, int iters){
  while (iters-- > 0){
    unsigned long long a, b;
    asm volatile("global_load_dwordx2 %0, %2, off sc0\n\t"
                 "global_load_dwordx2 %1, %2, off offset:8 sc0\n\t"
                 "s_waitcnt vmcnt(0)"
                 : "=&v"(a), "=&v"(b) : "v"(f) : "memory");
    if ((a & b) == FPAT) return true;
    __builtin_amdgcn_s_sleep(1);
  }
  return false;
}
__device__ inline void ld4x16_sc0(const h16* p0, const h16* p1,
                                  const h16* p2, const h16* p3,
                                  v4u& r0, v4u& r1, v4u& r2, v4u& r3){
  asm volatile("global_load_dwordx4 %0, %4, off sc0\n\t"
               "global_load_dwordx4 %1, %5, off sc0\n\t"
               "global_load_dwordx4 %2, %6, off sc0\n\t"
               "global_load_dwordx4 %3, %7, off sc0\n\t"
               "s_waitcnt vmcnt(0)"
               : "=&v"(r0), "=&v"(r1), "=&v"(r2), "=&v"(r3)
               : "v"(p0), "v"(p1), "v"(p2), "v"(p3) : "memory");
}
__device__ inline void st4x32_sc0(h16* p0, unsigned int w0, unsigned int w1,
                                  unsigned int w2, unsigned int w3){
  // consecutive local batches: +512 halves = +1024 B (13-bit offset ok)
  asm volatile("global_store_dword %0, %1, off sc0\n\t"
               "global_store_dword %0, %2, off offset:1024 sc0\n\t"
               "global_store_dword %0, %3, off offset:2048 sc0\n\t"
               "global_store_dword %0, %4, off offset:3072 sc0"
               :: "v"(p0), "v"(w0), "v"(w1), "v"(w2), "v"(w3) : "memory");
}
__device__ inline void st8_sc0(unsigned char* p, unsigned int v){
  asm volatile("global_store_byte %0, %1, off sc0" :: "v"(p), "v"(v) : "memory");
}

__device__ inline bool haszero8(unsigned long long x){
  return ((x - 0x0101010101010101ull) & ~x & 0x8080808080808080ull) != 0ull;
}

// One LSTM layer slice: this wg owns 32 hidden units x 4 gates for 16 batches.
// Structure = round-4 skeleton (5 barriers, tid0 polls, byte flags, LDS
// staging). mode0 (group verified on one XCD): self h-exchange + self flag
// additionally go through the XCD's L2 (sc0) — consumer prefers the L2 path
// and permanently downgrades to the agent path on first timeout (LDS
// broadcast), so correctness never depends on placement detection.
template<int KIN, bool XSRC>
__device__ void run_layer(const float* __restrict__ Wih, const float* __restrict__ Whh,
                          const float* __restrict__ bih, const float* __restrict__ bhh,
                          const float* __restrict__ xsrc,
                          const h16* __restrict__ src,
                          h16* __restrict__ dst, int dstMask,
                          unsigned char* flagSelf, const unsigned char* flagSrc,
                          unsigned char* fl2, h16* hb, int* modeSh, bool mode0,
                          int rg, int bg, h16* A)
{
  const int tid  = threadIdx.x;
  const int wv   = tid >> 6;
  const int lane = tid & 63;
  const int ISTR = KIN + 8;       // padded LDS row stride (halves)
  const int HOFF = 8320;          // h-region offset (halves), stride 520
  const int KI   = KIN / 32;

  const int n16  = lane & 15;
  const int unit = rg*32 + wv*8 + (n16 & 7);
  const int ksub = ((lane >> 4) & 3) * 8;
  const int row0 = ((n16 >> 3)    ) * 512 + unit;   // gate i (n<8) / f (n>=8)
  const int row1 = ((n16 >> 3) + 2) * 512 + unit;   // gate g / o

  // ---- prologue: load weight slices into register fragments (one-time)
  v8h wihf[KI][2];
  #pragma unroll
  for (int kk = 0; kk < KI; ++kk){
    #pragma unroll
    for (int j = 0; j < 2; ++j){
      const float* p = Wih + (size_t)(j ? row1 : row0) * KIN + kk*32 + ksub;
      v8h fr;
      #pragma unroll
      for (int e = 0; e < 8; ++e) fr[e] = (h16)p[e];
      wihf[kk][j] = fr;
    }
  }
  v8h whhf[16][2];
  #pragma unroll
  for (int kk = 0; kk < 16; ++kk){
    #pragma unroll
    for (int j = 0; j < 2; ++j){
      const float* p = Whh + (size_t)(j ? row1 : row0) * 512 + kk*32 + ksub;
      v8h fr;
      #pragma unroll
      for (int e = 0; e < 8; ++e) fr[e] = (h16)p[e];
      whhf[kk][j] = fr;
    }
  }
  const float bias0 = bih[row0] + bhh[row0];
  const float bias1 = bih[row1] + bhh[row1];
  float c[4] = {0.f, 0.f, 0.f, 0.f};
  const bool hi  = (lane & 8) != 0;
  const int  lb0 = (lane >> 4) << 2;      // local batch base for gate stores
  bool live = mode0;

  #pragma unroll 1
  for (int t = 0; t < 512; ++t){
    // ================= phase 1: input from layer below (always L3) =========
    if (!XSRC && tid == 0)
      wait_flag16((const unsigned long long*)(flagSrc + (size_t)t*16));
    __syncthreads();

    if constexpr (XSRC){
      #pragma unroll
      for (int i = 0; i < 2; ++i){
        int q = tid + i*256;
        int row = q >> 5, col = q & 31;          // 32 chunks x 8 halves per row
        const float* xp = xsrc + ((size_t)(bg*16 + row)*512 + t)*256 + col*8;
        float4 v0 = *(const float4*)(xp);
        float4 v1 = *(const float4*)(xp + 4);
        v8h o = {(h16)v0.x,(h16)v0.y,(h16)v0.z,(h16)v0.w,
                 (h16)v1.x,(h16)v1.y,(h16)v1.z,(h16)v1.w};
        *(v8h*)(A + row*ISTR + col*8) = o;
      }
    } else {
      unsigned long long a0[4], a1[4];
      #pragma unroll
      for (int i = 0; i < 4; ++i){
        int q = tid + i*256;
        int row = q >> 6, col = q & 63;          // 64 chunks x 8 halves per row
        const h16* sp = src + ((size_t)t*64 + bg*16 + row)*512 + col*8;
        a0[i] = cload64(sp);
        a1[i] = cload64(sp + 4);
      }
      #pragma unroll
      for (int i = 0; i < 4; ++i){
        int q = tid + i*256;
        int row = q >> 6, col = q & 63;
        union { unsigned long long u[2]; v8h h; } tmp;
        tmp.u[0] = a0[i]; tmp.u[1] = a1[i];
        *(v8h*)(A + row*ISTR + col*8) = tmp.h;
      }
    }
    __syncthreads();

    // agent pre-check (non-live path only); L3 latency hides behind W_ih.
    // live path resolves via a fast L2 poll at the resolve point instead.
    unsigned long long pa = FPAT, pb = FPAT;
    if (tid == 0 && t > 0 && !live){
      const unsigned long long* fs =
          (const unsigned long long*)(flagSelf + (size_t)(t-1)*16);
      pa = cload64(fs);
      pb = cload64(fs + 1);
    }

    v4f acc0 = {0.f, 0.f, 0.f, 0.f};
    v4f acc1 = {0.f, 0.f, 0.f, 0.f};
    const h16* Ain = A + n16*ISTR + ksub;
    #pragma unroll
    for (int kk = 0; kk < KI; ++kk){
      v8h a = *(const v8h*)(Ain + kk*32);
      acc0 = __builtin_amdgcn_mfma_f32_16x16x32_f16(a, wihf[kk][0], acc0, 0, 0, 0);
      acc1 = __builtin_amdgcn_mfma_f32_16x16x32_f16(a, wihf[kk][1], acc1, 0, 0, 0);
    }

    // ================= phase 2: recurrence =================
    if (tid == 0 && t > 0){
      if (live){
        if (!poll_l2_16(fl2 + (size_t)(t-1)*16, 16384)){
          *modeSh = 0;   // permanent downgrade to the agent path
          wait_flag16((const unsigned long long*)(flagSelf + (size_t)(t-1)*16));
        }
      } else if ((pa & pb) != FPAT){
        wait_flag16((const unsigned long long*)(flagSelf + (size_t)(t-1)*16));
      }
    }
    __syncthreads();
    live = (*modeSh != 0);

    if (t == 0){
      #pragma unroll
      for (int i = 0; i < 4; ++i){
        int q = tid + i*256;
        int row = q >> 6, col = q & 63;
        union { unsigned long long u[2]; v8h h; } tmp;
        tmp.u[0] = 0ull; tmp.u[1] = 0ull;
        *(v8h*)(A + HOFF + row*520 + col*8) = tmp.h;
      }
    } else if (live){
      // self h from the XCD-local L2 ping-pong buffer (local batch rows)
      const h16* hsrc = hb + (size_t)((t-1) & 1) * (16*512);
      const int row = tid >> 6, col = tid & 63;    // rows row, row+4, row+8, row+12
      const h16* q0 = hsrc + (size_t)(row     )*512 + col*8;
      v4u r0, r1, r2, r3;
      ld4x16_sc0(q0, q0 + 4*512, q0 + 8*512, q0 + 12*512, r0, r1, r2, r3);
      union { v4u u; v8h h; } cv;
      cv.u = r0; *(v8h*)(A + HOFF + (row     )*520 + col*8) = cv.h;
      cv.u = r1; *(v8h*)(A + HOFF + (row +  4)*520 + col*8) = cv.h;
      cv.u = r2; *(v8h*)(A + HOFF + (row +  8)*520 + col*8) = cv.h;
      cv.u = r3; *(v8h*)(A + HOFF + (row + 12)*520 + col*8) = cv.h;
    } else {
      const h16* hsrc = dst + (size_t)((t-1) & dstMask) * 64 * 512;
      unsigned long long a0[4], a1[4];
      #pragma unroll
      for (int i = 0; i < 4; ++i){
        int q = tid + i*256;
        int row = q >> 6, col = q & 63;
        const h16* sp = hsrc + (size_t)(bg*16 + row)*512 + col*8;
        a0[i] = cload64(sp);
        a1[i] = cload64(sp + 4);
      }
      #pragma unroll
      for (int i = 0; i < 4; ++i){
        int q = tid + i*256;
        int row = q >> 6, col = q & 63;
        union { unsigned long long u[2]; v8h h; } tmp;
        tmp.u[0] = a0[i]; tmp.u[1] = a1[i];
        *(v8h*)(A + HOFF + row*520 + col*8) = tmp.h;
      }
    }
    __syncthreads();

    const h16* Ah = A + HOFF + n16*520 + ksub;
    #pragma unroll
    for (int kk = 0; kk < 16; ++kk){
      v8h a = *(const v8h*)(Ah + kk*32);
      acc0 = __builtin_amdgcn_mfma_f32_16x16x32_f16(a, whhf[kk][0], acc0, 0, 0, 0);
      acc1 = __builtin_amdgcn_mfma_f32_16x16x32_f16(a, whhf[kk][1], acc1, 0, 0, 0);
    }

    // ---- gates: lane L holds (i|f) in acc0, (g|o) in acc1; partner is L^8
    h16* drow = dst + (size_t)(t & dstMask) * 64 * 512;
    unsigned int pk[4];
    #pragma unroll
    for (int r = 0; r < 4; ++r){
      float z0 = acc0[r] + bias0;
      float z1 = acc1[r] + bias1;
      float p0 = __shfl_xor(z0, 8, 64);
      float p1 = __shfl_xor(z1, 8, 64);
      float iv = hi ? p0 : z0;
      float fv = hi ? z0 : p0;
      float gv = hi ? p1 : z1;
      float ov = hi ? z1 : p1;
      iv = fsigmoid(iv); fv = fsigmoid(fv); ov = fsigmoid(ov);
      gv = ftanhf(gv);
      c[r] = fv * c[r] + iv * gv;
      float hval = ov * ftanhf(c[r]);
      h16 hh = (h16)hval;
      unsigned int mine = (unsigned int)__builtin_bit_cast(unsigned short, hh);
      unsigned int partner = (unsigned int)__shfl_xor((int)mine, 1, 64);
      pk[r] = mine | (partner << 16);
    }
    const bool wr = (!hi && !(n16 & 1));
    if (wr){
      if (mode0){
        h16* hrow = hb + (size_t)(t & 1) * (16*512) + (size_t)lb0*512 + unit;
        st4x32_sc0(hrow, pk[0], pk[1], pk[2], pk[3]);   // sc0 copy for self (L2)
      }
      #pragma unroll
      for (int r = 0; r < 4; ++r)                        // agent stream for layer above
        cstore32((void*)(drow + (size_t)(bg*16 + lb0 + r)*512 + unit), pk[r]);
    }
    __syncthreads();   // each wave's vmcnt(0) drains all its stores

    if (tid == 0){
      if (mode0) st8_sc0(fl2 + (size_t)t*16 + rg, 1u);   // L2 flag (same XCD)
      cstore8(flagSelf + (size_t)t*16 + rg, 1);          // L3 flag (always)
    }
  }
}

__global__ __launch_bounds__(256, 1) void lstm_persist(PParams p){
  __shared__ h16 A[16640];   // 33,280 B: in-region 16x520 + h-region 16x520
  __shared__ int modeSh;
  const int bx = blockIdx.x;
  const int g  = bx & 15;    // group = l*4+bg; its 16 wgs sit at bx==g (mod 16)
  const int rg = bx >> 4;    // -> one XCD (g&7) if dispatch is bx%8 round-robin
  const int l  = g >> 2;
  const int bg = g & 3;
  const int tid = threadIdx.x;

  // ---- one-time placement handshake: all 16 wgs of this group publish their
  // XCC_ID; mode0 = all equal (and sane). Detection only OPTIMIZES — the
  // consumer side downgrades on timeout, so a wrong verdict cannot hang or
  // corrupt (producers always dual-publish).
  unsigned int xcc = (unsigned int)__builtin_amdgcn_s_getreg(63508); // hwreg(20,0,32)=XCC_ID
  if (tid == 0){
    cstore8(p.xcctab + g*16 + rg, (unsigned char)((xcc & 63u) + 1u));
    const unsigned long long* tb = (const unsigned long long*)(p.xcctab + g*16);
    unsigned long long a = 0, b = 0;
    int it = 0;
    while (true){
      a = cload64(tb); b = cload64(tb + 1);
      if (!haszero8(a) && !haszero8(b)) break;
      __builtin_amdgcn_s_sleep(1);
      if (++it > (1 << 16)) break;
    }
    unsigned long long v = a & 0xffull;
    unsigned long long pat = v * 0x0101010101010101ull;
    modeSh = (a == pat && b == pat && v >= 1ull && v <= 8ull) ? 1 : 0;
  }
  __syncthreads();
  const bool mode0 = (modeSh != 0);

  unsigned char* fl  = p.flags  + (size_t)g * 512 * 16;
  unsigned char* fl2 = p.flagL2 + (size_t)g * 512 * 16;
  h16* hb = p.hbuf + (size_t)g * 2 * 16 * 512;

  if (l == 0){
    run_layer<256, true >(p.Wih[0], p.Whh[0], p.bih[0], p.bhh[0], p.x, nullptr,
                          p.s[0], 511, fl, nullptr, fl2, hb, &modeSh, mode0, rg, bg, A);
  } else {
    const unsigned char* fs = p.flags + (size_t)(g - 4) * 512 * 16;
    run_layer<512, false>(p.Wih[l], p.Whh[l], p.bih[l], p.bhh[l], nullptr, p.s[l-1],
                          p.s[l], (l == 3) ? 1 : 511, fl, fs, fl2, hb, &modeSh, mode0,
                          rg, bg, A);
  }
}

__global__ void head_k(const h16* __restrict__ h3, const float* __restrict__ Wo,
                       const float* __restrict__ bo, float* __restrict__ out){
  const int b = blockIdx.x;
  const int lane = threadIdx.x;
  float s = 0.f;
  for (int u = lane; u < 512; u += 64)
    s += (float)h3[(size_t)b * 512 + u] * Wo[u];
  #pragma unroll
  for (int off = 32; off; off >>= 1) s += __shfl_down(s, off, 64);
  if (lane == 0) out[b] = s + bo[0];
}

__global__ void zero_out_k(float* out, int n){
  int i = blockIdx.x * 64 + threadIdx.x;
  if (i < n) out[i] = 0.f;
}

extern "C" void kernel_launch(void* const* d_in, const int* in_sizes, int n_in,
                              void* d_out, int out_size, void* d_ws, size_t ws_size,
                              hipStream_t stream){
  PParams p;
  p.x = (const float*)d_in[0];
  for (int l = 0; l < 4; ++l){
    p.Wih[l] = (const float*)d_in[1 + 4*l + 0];
    p.Whh[l] = (const float*)d_in[1 + 4*l + 1];
    p.bih[l] = (const float*)d_in[1 + 4*l + 2];
    p.bhh[l] = (const float*)d_in[1 + 4*l + 3];
  }
  const float* Wo = (const float*)d_in[17];
  const float* bo = (const float*)d_in[18];

  // workspace layout
  const size_t FLAGS_OFF  = 0;                         // [16][512][16] B = 128 KB
  const size_t FLAG2_OFF  = 131072;                    // [16][512][16] B = 128 KB
  const size_t XCC_OFF    = 262144;                    // [16][16] B (pad 1 KB)
  const size_t HBUF_OFF   = 263168;                    // [16][2][16][512] h16 = 512 KB
  const size_t STREAM_OFF = 263168 + 524288;           // = 787456
  const size_t SBYTES     = (size_t)512 * 64 * 512 * 2; // 32 MB per full stream
  const size_t NEED       = STREAM_OFF + 3 * SBYTES + (size_t)2 * 64 * 512 * 2;

  if (ws_size < NEED){
    zero_out_k<<<dim3(1), dim3(64), 0, stream>>>((float*)d_out, out_size);
    return;
  }

  char* ws = (char*)d_ws;
  p.flags  = (unsigned char*)(ws + FLAGS_OFF);
  p.flagL2 = (unsigned char*)(ws + FLAG2_OFF);
  p.xcctab = (unsigned char*)(ws + XCC_OFF);
  p.hbuf   = (h16*)(ws + HBUF_OFF);
  size_t off = STREAM_OFF;
  for (int l = 0; l < 3; ++l){ p.s[l] = (h16*)(ws + off); off += SBYTES; }
  p.s[3] = (h16*)(ws + off);

  hipMemsetAsync(ws, 0, XCC_OFF + 1024, stream);   // flags + flagL2 + xcctab

  void* args[] = { &p };
  hipError_t e = hipLaunchCooperativeKernel((void*)lstm_persist, dim3(256), dim3(256),
                                            args, 0, stream);
  if (e != hipSuccess){
    // fallback: plain launch; 256 blocks @ 1 wg/CU co-reside on 256 CUs
    lstm_persist<<<dim3(256), dim3(256), 0, stream>>>(p);
  }

  // final timestep t=511 lives in s3 buffer (511 & 1) == 1
  head_k<<<dim3(64), dim3(64), 0, stream>>>(p.s[3] + (size_t)64 * 512, Wo, bo, (float*)d_out);
}

// Round 6
// 3160.536 us; speedup vs baseline: 1.5170x; 1.5170x over previous
//
#include <hip/hip_runtime.h>
#include <hip/hip_fp16.h>

typedef _Float16 h16;
typedef _Float16 v8h  __attribute__((ext_vector_type(8)));
typedef float    v4f  __attribute__((ext_vector_type(4)));

// all-16-producers-done pattern: 16 bytes each == 1
#define FPAT 0x0101010101010101ull
// parity stride of the tagged self buffer, in u32 words: [2][16 g][16 b][512 u]
#define PSTR (16 * 16 * 512)

struct PParams {
  const float* x;                 // [64][512][256] fp32
  const float* Wih[4];            // [2048][KIN]
  const float* Whh[4];            // [2048][512]
  const float* bih[4];
  const float* bhh[4];
  h16* s[4];                      // streams: l=0..2 [512][64][512], l=3 [2][64][512]
  unsigned char* flags;           // [16 g][512 t][16 wg] bytes (cross-layer sync)
  unsigned int* selfb;            // [2][16 g][16 b][512 u] tagged h words (self sync)
};

__device__ inline float fsigmoid(float x){
  float e = __builtin_amdgcn_exp2f(-1.4426950408889634f * __builtin_fabsf(x));
  float r = __builtin_amdgcn_rcpf(1.0f + e);
  return x >= 0.f ? r : e * r;
}
__device__ inline float ftanhf(float x){
  float e = __builtin_amdgcn_exp2f(-2.8853900817779268f * __builtin_fabsf(x));
  float t = (1.0f - e) * __builtin_amdgcn_rcpf(1.0f + e);
  return x >= 0.f ? t : -t;
}

// Fine-grained agent-coherent ops: write-through to the coherence point /
// read-through past the non-coherent per-XCD L2. Proven rounds 0/4.
__device__ inline unsigned long long cload64(const void* p){
  return __hip_atomic_load((const unsigned long long*)p, __ATOMIC_RELAXED,
                           __HIP_MEMORY_SCOPE_AGENT);
}
__device__ inline void cstore32(void* p, unsigned int v){
  __hip_atomic_store((unsigned int*)p, v, __ATOMIC_RELAXED, __HIP_MEMORY_SCOPE_AGENT);
}
__device__ inline void cstore8(void* p, unsigned char v){
  __hip_atomic_store((unsigned char*)p, v, __ATOMIC_RELAXED, __HIP_MEMORY_SCOPE_AGENT);
}

__device__ inline void wait_flag16(const unsigned long long* f){
  int it = 0;
  while (true){
    unsigned long long a = cload64(f);
    unsigned long long b = cload64(f + 1);
    if ((a & b) == FPAT) break;
    __builtin_amdgcn_s_sleep(1);
    if (++it > (1 << 21)) break;   // safety valve: never hang the harness
  }
}

// One LSTM layer slice: this wg owns 32 hidden units x 4 gates for 16 batches.
// Self-recurrence sync is TAG-IN-DATA: h words are stored as {h16 | (t+1)<<16}
// in a parity ping-pong buffer; the consumer's staging loads retry until the
// tag matches, so the producer needs NO drain and NO flag on the self path.
// Race-freedom: a peer can only write step t+1 into parity (t+1)&1 == (t-1)&1
// after it observed ALL step-t tags, which requires this wg's step-t stage
// (the read in question) to have completed. Cross-layer sync keeps the proven
// byte-flag path. 3 barriers/step (was 5).
template<int KIN, bool XSRC>
__device__ void run_layer(const float* __restrict__ Wih, const float* __restrict__ Whh,
                          const float* __restrict__ bih, const float* __restrict__ bhh,
                          const float* __restrict__ xsrc,
                          const h16* __restrict__ src,
                          h16* __restrict__ dst, int dstMask,
                          unsigned int* selfb,
                          unsigned char* flagSelf, const unsigned char* flagSrc,
                          int rg, int bg, h16* A)
{
  const int tid  = threadIdx.x;
  const int wv   = tid >> 6;
  const int lane = tid & 63;
  const int ISTR = KIN + 8;       // padded LDS row stride (halves)
  const int HOFF = 8320;          // h-region offset (halves), stride 520
  const int KI   = KIN / 32;

  const int n16  = lane & 15;
  const int unit = rg*32 + wv*8 + (n16 & 7);
  const int ksub = ((lane >> 4) & 3) * 8;
  const int row0 = ((n16 >> 3)    ) * 512 + unit;   // gate i (n<8) / f (n>=8)
  const int row1 = ((n16 >> 3) + 2) * 512 + unit;   // gate g / o

  // self-stage chunk coordinates: 8 chunks/thread, chunk = 4 consecutive units
  const int srow = tid >> 7;       // + 2*i -> local batch rows 0..15
  const int scol = tid & 127;      // unit quad 0..127

  // ---- prologue: load weight slices into register fragments (one-time)
  v8h wihf[KI][2];
  #pragma unroll
  for (int kk = 0; kk < KI; ++kk){
    #pragma unroll
    for (int j = 0; j < 2; ++j){
      const float* p = Wih + (size_t)(j ? row1 : row0) * KIN + kk*32 + ksub;
      v8h fr;
      #pragma unroll
      for (int e = 0; e < 8; ++e) fr[e] = (h16)p[e];
      wihf[kk][j] = fr;
    }
  }
  v8h whhf[16][2];
  #pragma unroll
  for (int kk = 0; kk < 16; ++kk){
    #pragma unroll
    for (int j = 0; j < 2; ++j){
      const float* p = Whh + (size_t)(j ? row1 : row0) * 512 + kk*32 + ksub;
      v8h fr;
      #pragma unroll
      for (int e = 0; e < 8; ++e) fr[e] = (h16)p[e];
      whhf[kk][j] = fr;
    }
  }
  const float bias0 = bih[row0] + bhh[row0];
  const float bias1 = bih[row1] + bhh[row1];
  float c[4] = {0.f, 0.f, 0.f, 0.f};
  const bool hi = (lane & 8) != 0;

  #pragma unroll 1
  for (int t = 0; t < 512; ++t){
    // ---- self pass-1: issue tagged h(t-1) loads FIRST (they age toward L3
    // visibility while the src flag resolves and src data stages).
    unsigned long long w0[8], w1[8];
    if (t > 0){
      const unsigned int* sb = selfb + (size_t)((t-1) & 1) * PSTR;
      #pragma unroll
      for (int i = 0; i < 8; ++i){
        const unsigned int* cp = sb + (size_t)(srow + 2*i)*512 + scol*4;
        w0[i] = cload64(cp);
        w1[i] = cload64(cp + 2);
      }
    }

    // ---- cross-layer src flag (usually already set: lower layer runs ahead)
    if (!XSRC && tid == 0)
      wait_flag16((const unsigned long long*)(flagSrc + (size_t)t*16));
    __syncthreads();   // B1: src-ready broadcast; prev-step LDS reads done

    // ---- stage src(t) -> in-region
    if constexpr (XSRC){
      #pragma unroll
      for (int i = 0; i < 2; ++i){
        int q = tid + i*256;
        int row = q >> 5, col = q & 31;          // 32 chunks x 8 halves per row
        const float* xp = xsrc + ((size_t)(bg*16 + row)*512 + t)*256 + col*8;
        float4 v0 = *(const float4*)(xp);
        float4 v1 = *(const float4*)(xp + 4);
        v8h o = {(h16)v0.x,(h16)v0.y,(h16)v0.z,(h16)v0.w,
                 (h16)v1.x,(h16)v1.y,(h16)v1.z,(h16)v1.w};
        *(v8h*)(A + row*ISTR + col*8) = o;
      }
    } else {
      unsigned long long a0[4], a1[4];
      #pragma unroll
      for (int i = 0; i < 4; ++i){
        int q = tid + i*256;
        int row = q >> 6, col = q & 63;          // 64 chunks x 8 halves per row
        const h16* sp = src + ((size_t)t*64 + bg*16 + row)*512 + col*8;
        a0[i] = cload64(sp);
        a1[i] = cload64(sp + 4);
      }
      #pragma unroll
      for (int i = 0; i < 4; ++i){
        int q = tid + i*256;
        int row = q >> 6, col = q & 63;
        union { unsigned long long u[2]; v8h h; } tmp;
        tmp.u[0] = a0[i]; tmp.u[1] = a1[i];
        *(v8h*)(A + row*ISTR + col*8) = tmp.h;
      }
    }

    // ---- self validate/retry -> h-region (tag == t means h(t-1) is fresh)
    if (t == 0){
      #pragma unroll
      for (int i = 0; i < 4; ++i){
        int q = tid + i*256;
        int row = q >> 6, col = q & 63;
        union { unsigned long long u[2]; v8h h; } tmp;
        tmp.u[0] = 0ull; tmp.u[1] = 0ull;
        *(v8h*)(A + HOFF + row*520 + col*8) = tmp.h;
      }
    } else {
      const unsigned int* sb = selfb + (size_t)((t-1) & 1) * PSTR;
      const unsigned long long M  = 0xFFFF0000FFFF0000ull;
      const unsigned long long TP = ((unsigned long long)t << 16)
                                  | ((unsigned long long)t << 48);
      unsigned pend = 0xffu;
      int it = 0;
      while (true){
        #pragma unroll
        for (int i = 0; i < 8; ++i){
          if (pend & (1u << i)){
            if ((w0[i] & M) == TP && (w1[i] & M) == TP){
              unsigned long long pk =  (w0[i] & 0xFFFFull)
                                    | (((w0[i] >> 32) & 0xFFFFull) << 16)
                                    | ((w1[i] & 0xFFFFull) << 32)
                                    | (((w1[i] >> 32) & 0xFFFFull) << 48);
              int row = srow + 2*i;
              *(unsigned long long*)(A + HOFF + row*520 + scol*4) = pk;
              pend &= ~(1u << i);
            }
          }
        }
        if (!pend || ++it > (1 << 14)) break;   // safety valve
        #pragma unroll
        for (int i = 0; i < 8; ++i){
          if (pend & (1u << i)){
            const unsigned int* cp = sb + (size_t)(srow + 2*i)*512 + scol*4;
            w0[i] = cload64(cp);
            w1[i] = cload64(cp + 2);
          }
        }
      }
    }
    __syncthreads();   // B2: both LDS regions staged

    // ---- MFMA: W_ih then W_hh, two accumulator chains
    v4f acc0 = {0.f, 0.f, 0.f, 0.f};
    v4f acc1 = {0.f, 0.f, 0.f, 0.f};
    const h16* Ain = A + n16*ISTR + ksub;
    #pragma unroll
    for (int kk = 0; kk < KI; ++kk){
      v8h a = *(const v8h*)(Ain + kk*32);
      acc0 = __builtin_amdgcn_mfma_f32_16x16x32_f16(a, wihf[kk][0], acc0, 0, 0, 0);
      acc1 = __builtin_amdgcn_mfma_f32_16x16x32_f16(a, wihf[kk][1], acc1, 0, 0, 0);
    }
    const h16* Ah = A + HOFF + n16*520 + ksub;
    #pragma unroll
    for (int kk = 0; kk < 16; ++kk){
      v8h a = *(const v8h*)(Ah + kk*32);
      acc0 = __builtin_amdgcn_mfma_f32_16x16x32_f16(a, whhf[kk][0], acc0, 0, 0, 0);
      acc1 = __builtin_amdgcn_mfma_f32_16x16x32_f16(a, whhf[kk][1], acc1, 0, 0, 0);
    }

    // ---- gates: lane L holds (i|f) in acc0, (g|o) in acc1; partner is L^8
    h16* drow = dst + (size_t)(t & dstMask) * 64 * 512;
    unsigned int* sbW = selfb + (size_t)(t & 1) * PSTR;
    const unsigned int mytag = ((unsigned)(t + 1)) << 16;
    #pragma unroll
    for (int r = 0; r < 4; ++r){
      float z0 = acc0[r] + bias0;
      float z1 = acc1[r] + bias1;
      float p0 = __shfl_xor(z0, 8, 64);
      float p1 = __shfl_xor(z1, 8, 64);
      float iv = hi ? p0 : z0;
      float fv = hi ? z0 : p0;
      float gv = hi ? p1 : z1;
      float ov = hi ? z1 : p1;
      iv = fsigmoid(iv); fv = fsigmoid(fv); ov = fsigmoid(ov);
      gv = ftanhf(gv);
      c[r] = fv * c[r] + iv * gv;
      float hval = ov * ftanhf(c[r]);
      h16 hh = (h16)hval;
      unsigned int mine = (unsigned int)__builtin_bit_cast(unsigned short, hh);
      unsigned int partner = (unsigned int)__shfl_xor((int)mine, 1, 64);
      if (!hi){
        int lb = ((lane >> 4) << 2) + r;                   // local batch 0..15
        // tagged self word: fire-and-forget, no drain needed before consumers
        cstore32((void*)(sbW + (size_t)lb*512 + unit), mine | mytag);
        if (!(n16 & 1)){
          // packed 2-unit word for the cross-layer stream (and head)
          cstore32((void*)(drow + (size_t)(bg*16 + lb)*512 + unit),
                   mine | (partner << 16));
        }
      }
    }
    __syncthreads();   // B3: per-wave vmcnt(0) drains stores for the flag below

    if (tid == 0)
      cstore8(flagSelf + (size_t)t*16 + rg, 1);
  }
}

__global__ __launch_bounds__(256, 1) void lstm_persist(PParams p){
  __shared__ h16 A[16640];   // 33,280 B: in-region 16x520 + h-region 16x520
  const int bx = blockIdx.x;
  const int l  = bx >> 6;
  const int rg = (bx >> 2) & 15;
  const int bg = bx & 3;
  const int g  = l*4 + bg;
  unsigned char* fl = p.flags + (size_t)g * 512 * 16;
  unsigned int*  sb = p.selfb + (size_t)g * (16 * 512);
  if (l == 0){
    run_layer<256, true >(p.Wih[0], p.Whh[0], p.bih[0], p.bhh[0], p.x, nullptr,
                          p.s[0], 511, sb, fl, nullptr, rg, bg, A);
  } else {
    const unsigned char* fs = p.flags + (size_t)(g - 4) * 512 * 16;
    run_layer<512, false>(p.Wih[l], p.Whh[l], p.bih[l], p.bhh[l], nullptr, p.s[l-1],
                          p.s[l], (l == 3) ? 1 : 511, sb, fl, fs, rg, bg, A);
  }
}

__global__ void head_k(const h16* __restrict__ h3, const float* __restrict__ Wo,
                       const float* __restrict__ bo, float* __restrict__ out){
  const int b = blockIdx.x;
  const int lane = threadIdx.x;
  float s = 0.f;
  for (int u = lane; u < 512; u += 64)
    s += (float)h3[(size_t)b * 512 + u] * Wo[u];
  #pragma unroll
  for (int off = 32; off; off >>= 1) s += __shfl_down(s, off, 64);
  if (lane == 0) out[b] = s + bo[0];
}

__global__ void zero_out_k(float* out, int n){
  int i = blockIdx.x * 64 + threadIdx.x;
  if (i < n) out[i] = 0.f;
}

extern "C" void kernel_launch(void* const* d_in, const int* in_sizes, int n_in,
                              void* d_out, int out_size, void* d_ws, size_t ws_size,
                              hipStream_t stream){
  PParams p;
  p.x = (const float*)d_in[0];
  for (int l = 0; l < 4; ++l){
    p.Wih[l] = (const float*)d_in[1 + 4*l + 0];
    p.Whh[l] = (const float*)d_in[1 + 4*l + 1];
    p.bih[l] = (const float*)d_in[1 + 4*l + 2];
    p.bhh[l] = (const float*)d_in[1 + 4*l + 3];
  }
  const float* Wo = (const float*)d_in[17];
  const float* bo = (const float*)d_in[18];

  // workspace layout
  const size_t FLAG_BYTES = (size_t)16 * 512 * 16;                 // 128 KB
  const size_t SELF_BYTES = (size_t)2 * 16 * 16 * 512 * 4;         // 1 MB
  const size_t STREAM_OFF = FLAG_BYTES + SELF_BYTES;
  const size_t SBYTES     = (size_t)512 * 64 * 512 * 2;            // 32 MB per stream
  const size_t NEED       = STREAM_OFF + 3 * SBYTES + (size_t)2 * 64 * 512 * 2;

  if (ws_size < NEED){
    zero_out_k<<<dim3(1), dim3(64), 0, stream>>>((float*)d_out, out_size);
    return;
  }

  char* ws = (char*)d_ws;
  p.flags = (unsigned char*)ws;
  p.selfb = (unsigned int*)(ws + FLAG_BYTES);
  size_t off = STREAM_OFF;
  for (int l = 0; l < 3; ++l){ p.s[l] = (h16*)(ws + off); off += SBYTES; }
  p.s[3] = (h16*)(ws + off);

  // zero flags + tagged self buffer (tags restart at 1 each launch)
  hipMemsetAsync(ws, 0, FLAG_BYTES + SELF_BYTES, stream);

  void* args[] = { &p };
  hipError_t e = hipLaunchCooperativeKernel((void*)lstm_persist, dim3(256), dim3(256),
                                            args, 0, stream);
  if (e != hipSuccess){
    // fallback: plain launch; 256 blocks @ 1 wg/CU co-reside on 256 CUs
    lstm_persist<<<dim3(256), dim3(256), 0, stream>>>(p);
  }

  // final timestep t=511 lives in s3 buffer (511 & 1) == 1
  head_k<<<dim3(64), dim3(64), 0, stream>>>(p.s[3] + (size_t)64 * 512, Wo, bo, (float*)d_out);
}

// Round 7
// 1908.957 us; speedup vs baseline: 2.5116x; 1.6556x over previous
//
#include <hip/hip_runtime.h>
#include <hip/hip_fp16.h>

typedef _Float16 h16;
typedef _Float16 v8h  __attribute__((ext_vector_type(8)));
typedef float    v4f  __attribute__((ext_vector_type(4)));

// all-16-producers-done pattern: 16 bytes each == 1
#define FPAT 0x0101010101010101ull

struct PParams {
  const float* x;                 // [64][512][256] fp32
  const float* Wih[4];            // [2048][KIN]
  const float* Whh[4];            // [2048][512]
  const float* bih[4];
  const float* bhh[4];
  h16* s[4];                      // streams: l=0..2 [512][64][512], l=3 [2][64][512]
  unsigned char* flags;           // [16 g][512 t][16 wg] bytes, 0 -> 1
};

__device__ inline float fsigmoid(float x){
  float e = __builtin_amdgcn_exp2f(-1.4426950408889634f * __builtin_fabsf(x));
  float r = __builtin_amdgcn_rcpf(1.0f + e);
  return x >= 0.f ? r : e * r;
}
__device__ inline float ftanhf(float x){
  float e = __builtin_amdgcn_exp2f(-2.8853900817779268f * __builtin_fabsf(x));
  float t = (1.0f - e) * __builtin_amdgcn_rcpf(1.0f + e);
  return x >= 0.f ? t : -t;
}

// Fine-grained agent-coherent ops: write-through to the coherence point /
// read-through past the non-coherent per-XCD L2. Proven rounds 0/4.
__device__ inline unsigned long long cload64(const void* p){
  return __hip_atomic_load((const unsigned long long*)p, __ATOMIC_RELAXED,
                           __HIP_MEMORY_SCOPE_AGENT);
}
__device__ inline void cstore32(void* p, unsigned int v){
  __hip_atomic_store((unsigned int*)p, v, __ATOMIC_RELAXED, __HIP_MEMORY_SCOPE_AGENT);
}
__device__ inline void cstore8(void* p, unsigned char v){
  __hip_atomic_store((unsigned char*)p, v, __ATOMIC_RELAXED, __HIP_MEMORY_SCOPE_AGENT);
}

// Per-WAVE flag wait: lane0 polls the 16 producer bytes (two 8B agent loads),
// result broadcast in-register via __shfl — no workgroup barrier needed to
// propagate the verdict. 4 pollers/wg (vs round-2's failed 256-lane storm).
__device__ inline void wave_wait16(const unsigned long long* f, int lane){
  int it = 0;
  while (true){
    unsigned long long a = FPAT, b = FPAT;
    if (lane == 0){ a = cload64(f); b = cload64(f + 1); }
    if (__shfl((int)((a & b) == FPAT), 0, 64)) break;
    __builtin_amdgcn_s_sleep(1);
    if (++it > (1 << 21)) break;   // safety valve: never hang the harness
  }
}

// One LSTM layer slice: this wg owns 32 hidden units x 4 gates for 16 batches.
// Weights live in VGPR/AGPR as MFMA B-fragments; c stays in fp32 registers.
// Step: [wave src-poll] -> stage src(t) -> B1 -> W_ih (self pre-check load in
// flight under it) -> [wave self-resolve] -> stage h(t-1) -> B2 -> W_hh ->
// gates -> stores -> B3(drain) -> flag. 3 barriers (was 5): B1/B2 are the LDS
// write->read hazards, B3 the store drain; broadcast barriers replaced by
// per-wave polls. Staging loads are PLAIN 128-bit for fresh-per-t streams
// (flag-gated first touch -> no stale-L2 hazard); SAGENT=true (layer 3's
// 2-deep ping-pong, addresses reuse) keeps agent-scope loads.
template<int KIN, bool XSRC, bool SAGENT>
__device__ void run_layer(const float* __restrict__ Wih, const float* __restrict__ Whh,
                          const float* __restrict__ bih, const float* __restrict__ bhh,
                          const float* __restrict__ xsrc,
                          const h16* __restrict__ src,
                          h16* __restrict__ dst, int dstMask,
                          unsigned char* flagSelf, const unsigned char* flagSrc,
                          int rg, int bg, h16* A)
{
  const int tid  = threadIdx.x;
  const int wv   = tid >> 6;
  const int lane = tid & 63;
  const int ISTR = KIN + 8;       // padded LDS row stride (halves)
  const int HOFF = 8320;          // h-region offset (halves), stride 520
  const int KI   = KIN / 32;

  const int n16  = lane & 15;
  const int unit = rg*32 + wv*8 + (n16 & 7);
  const int ksub = ((lane >> 4) & 3) * 8;
  const int row0 = ((n16 >> 3)    ) * 512 + unit;   // gate i (n<8) / f (n>=8)
  const int row1 = ((n16 >> 3) + 2) * 512 + unit;   // gate g / o

  // ---- prologue: load weight slices into register fragments (one-time)
  v8h wihf[KI][2];
  #pragma unroll
  for (int kk = 0; kk < KI; ++kk){
    #pragma unroll
    for (int j = 0; j < 2; ++j){
      const float* p = Wih + (size_t)(j ? row1 : row0) * KIN + kk*32 + ksub;
      v8h fr;
      #pragma unroll
      for (int e = 0; e < 8; ++e) fr[e] = (h16)p[e];
      wihf[kk][j] = fr;
    }
  }
  v8h whhf[16][2];
  #pragma unroll
  for (int kk = 0; kk < 16; ++kk){
    #pragma unroll
    for (int j = 0; j < 2; ++j){
      const float* p = Whh + (size_t)(j ? row1 : row0) * 512 + kk*32 + ksub;
      v8h fr;
      #pragma unroll
      for (int e = 0; e < 8; ++e) fr[e] = (h16)p[e];
      whhf[kk][j] = fr;
    }
  }
  const float bias0 = bih[row0] + bhh[row0];
  const float bias1 = bih[row1] + bhh[row1];
  float c[4] = {0.f, 0.f, 0.f, 0.f};
  const bool hi = (lane & 8) != 0;

  #pragma unroll 1
  for (int t = 0; t < 512; ++t){
    // ================= phase 1: input from layer below =================
    if constexpr (!XSRC)
      wave_wait16((const unsigned long long*)(flagSrc + (size_t)t*16), lane);

    if constexpr (XSRC){
      #pragma unroll
      for (int i = 0; i < 2; ++i){
        int q = tid + i*256;
        int row = q >> 5, col = q & 31;          // 32 chunks x 8 halves per row
        const float* xp = xsrc + ((size_t)(bg*16 + row)*512 + t)*256 + col*8;
        float4 v0 = *(const float4*)(xp);
        float4 v1 = *(const float4*)(xp + 4);
        v8h o = {(h16)v0.x,(h16)v0.y,(h16)v0.z,(h16)v0.w,
                 (h16)v1.x,(h16)v1.y,(h16)v1.z,(h16)v1.w};
        *(v8h*)(A + row*ISTR + col*8) = o;
      }
    } else {
      // fresh-per-t stream, flag-gated first touch -> plain 128-bit loads
      v8h hv[4];
      #pragma unroll
      for (int i = 0; i < 4; ++i){
        int q = tid + i*256;
        int row = q >> 6, col = q & 63;          // 64 chunks x 8 halves per row
        hv[i] = *(const v8h*)(src + ((size_t)t*64 + bg*16 + row)*512 + col*8);
      }
      #pragma unroll
      for (int i = 0; i < 4; ++i){
        int q = tid + i*256;
        int row = q >> 6, col = q & 63;
        *(v8h*)(A + row*ISTR + col*8) = hv[i];
      }
    }
    __syncthreads();   // B1: stage-in writes -> W_ih reads

    // per-wave self pre-check: lane0's loads age toward L3 under the W_ih chain
    unsigned long long pa = FPAT, pb = FPAT;
    const unsigned long long* fsPrev =
        (const unsigned long long*)(flagSelf + (size_t)(t-1)*16);
    if (t > 0 && lane == 0){
      pa = cload64(fsPrev);
      pb = cload64(fsPrev + 1);
    }

    v4f a0e = {0.f,0.f,0.f,0.f}, a0o = {0.f,0.f,0.f,0.f};
    v4f a1e = {0.f,0.f,0.f,0.f}, a1o = {0.f,0.f,0.f,0.f};
    const h16* Ain = A + n16*ISTR + ksub;
    #pragma unroll
    for (int kk = 0; kk < KI; ++kk){
      v8h a = *(const v8h*)(Ain + kk*32);
      if (kk & 1){
        a0o = __builtin_amdgcn_mfma_f32_16x16x32_f16(a, wihf[kk][0], a0o, 0, 0, 0);
        a1o = __builtin_amdgcn_mfma_f32_16x16x32_f16(a, wihf[kk][1], a1o, 0, 0, 0);
      } else {
        a0e = __builtin_amdgcn_mfma_f32_16x16x32_f16(a, wihf[kk][0], a0e, 0, 0, 0);
        a1e = __builtin_amdgcn_mfma_f32_16x16x32_f16(a, wihf[kk][1], a1e, 0, 0, 0);
      }
    }

    // ================= phase 2: recurrence =================
    if (t > 0){
      if (!__shfl((int)((pa & pb) == FPAT), 0, 64))
        wave_wait16(fsPrev, lane);
    }

    if (t == 0){
      #pragma unroll
      for (int i = 0; i < 4; ++i){
        int q = tid + i*256;
        int row = q >> 6, col = q & 63;
        union { unsigned long long u[2]; v8h h; } tmp;
        tmp.u[0] = 0ull; tmp.u[1] = 0ull;
        *(v8h*)(A + HOFF + row*520 + col*8) = tmp.h;
      }
    } else if constexpr (SAGENT){
      // layer 3: 2-deep ping-pong reuses addresses -> agent-scope loads
      const h16* hsrc = dst + (size_t)((t-1) & dstMask) * 64 * 512;
      unsigned long long a0[4], a1[4];
      #pragma unroll
      for (int i = 0; i < 4; ++i){
        int q = tid + i*256;
        int row = q >> 6, col = q & 63;
        const h16* sp = hsrc + (size_t)(bg*16 + row)*512 + col*8;
        a0[i] = cload64(sp);
        a1[i] = cload64(sp + 4);
      }
      #pragma unroll
      for (int i = 0; i < 4; ++i){
        int q = tid + i*256;
        int row = q >> 6, col = q & 63;
        union { unsigned long long u[2]; v8h h; } tmp;
        tmp.u[0] = a0[i]; tmp.u[1] = a1[i];
        *(v8h*)(A + HOFF + row*520 + col*8) = tmp.h;
      }
    } else {
      // fresh-per-t stream, flag-gated first touch -> plain 128-bit loads
      const h16* hsrc = dst + (size_t)((t-1) & dstMask) * 64 * 512;
      v8h hv[4];
      #pragma unroll
      for (int i = 0; i < 4; ++i){
        int q = tid + i*256;
        int row = q >> 6, col = q & 63;
        hv[i] = *(const v8h*)(hsrc + (size_t)(bg*16 + row)*512 + col*8);
      }
      #pragma unroll
      for (int i = 0; i < 4; ++i){
        int q = tid + i*256;
        int row = q >> 6, col = q & 63;
        *(v8h*)(A + HOFF + row*520 + col*8) = hv[i];
      }
    }
    __syncthreads();   // B2: stage-h writes -> W_hh reads

    const h16* Ah = A + HOFF + n16*520 + ksub;
    #pragma unroll
    for (int kk = 0; kk < 16; ++kk){
      v8h a = *(const v8h*)(Ah + kk*32);
      if (kk & 1){
        a0o = __builtin_amdgcn_mfma_f32_16x16x32_f16(a, whhf[kk][0], a0o, 0, 0, 0);
        a1o = __builtin_amdgcn_mfma_f32_16x16x32_f16(a, whhf[kk][1], a1o, 0, 0, 0);
      } else {
        a0e = __builtin_amdgcn_mfma_f32_16x16x32_f16(a, whhf[kk][0], a0e, 0, 0, 0);
        a1e = __builtin_amdgcn_mfma_f32_16x16x32_f16(a, whhf[kk][1], a1e, 0, 0, 0);
      }
    }

    // ---- gates: lane L holds (i|f) in acc0, (g|o) in acc1; partner is L^8
    h16* drow = dst + (size_t)(t & dstMask) * 64 * 512;
    #pragma unroll
    for (int r = 0; r < 4; ++r){
      float z0 = a0e[r] + a0o[r] + bias0;
      float z1 = a1e[r] + a1o[r] + bias1;
      float p0 = __shfl_xor(z0, 8, 64);
      float p1 = __shfl_xor(z1, 8, 64);
      float iv = hi ? p0 : z0;
      float fv = hi ? z0 : p0;
      float gv = hi ? p1 : z1;
      float ov = hi ? z1 : p1;
      iv = fsigmoid(iv); fv = fsigmoid(fv); ov = fsigmoid(ov);
      gv = ftanhf(gv);
      c[r] = fv * c[r] + iv * gv;
      float hval = ov * ftanhf(c[r]);
      h16 hh = (h16)hval;
      unsigned int mine = (unsigned int)__builtin_bit_cast(unsigned short, hh);
      unsigned int partner = (unsigned int)__shfl_xor((int)mine, 1, 64);
      if (!hi && !(n16 & 1)){
        int batch = bg*16 + ((lane >> 4) << 2) + r;
        // packed 2-unit write-through store -> visible at the coherence point
        cstore32((void*)(drow + (size_t)batch*512 + unit), mine | (partner << 16));
      }
    }
    __syncthreads();   // B3: each wave's vmcnt(0) drains write-through stores

    // publish: one independent fire-and-forget byte store per wg
    if (tid == 0)
      cstore8(flagSelf + (size_t)t*16 + rg, 1);
  }
}

__global__ __launch_bounds__(256, 1) void lstm_persist(PParams p){
  __shared__ h16 A[16640];   // 33,280 B: in-region 16x520 + h-region 16x520
  const int bx = blockIdx.x;
  const int l  = bx >> 6;
  const int rg = (bx >> 2) & 15;
  const int bg = bx & 3;
  unsigned char* fl = p.flags + (size_t)(l*4 + bg) * 512 * 16;
  if (l == 0){
    run_layer<256, true,  false>(p.Wih[0], p.Whh[0], p.bih[0], p.bhh[0], p.x, nullptr,
                                 p.s[0], 511, fl, nullptr, rg, bg, A);
  } else if (l < 3){
    const unsigned char* fs = p.flags + (size_t)((l-1)*4 + bg) * 512 * 16;
    run_layer<512, false, false>(p.Wih[l], p.Whh[l], p.bih[l], p.bhh[l], nullptr,
                                 p.s[l-1], p.s[l], 511, fl, fs, rg, bg, A);
  } else {
    const unsigned char* fs = p.flags + (size_t)(2*4 + bg) * 512 * 16;
    run_layer<512, false, true >(p.Wih[3], p.Whh[3], p.bih[3], p.bhh[3], nullptr,
                                 p.s[2], p.s[3], 1, fl, fs, rg, bg, A);
  }
}

__global__ void head_k(const h16* __restrict__ h3, const float* __restrict__ Wo,
                       const float* __restrict__ bo, float* __restrict__ out){
  const int b = blockIdx.x;
  const int lane = threadIdx.x;
  float s = 0.f;
  for (int u = lane; u < 512; u += 64)
    s += (float)h3[(size_t)b * 512 + u] * Wo[u];
  #pragma unroll
  for (int off = 32; off; off >>= 1) s += __shfl_down(s, off, 64);
  if (lane == 0) out[b] = s + bo[0];
}

__global__ void zero_out_k(float* out, int n){
  int i = blockIdx.x * 64 + threadIdx.x;
  if (i < n) out[i] = 0.f;
}

extern "C" void kernel_launch(void* const* d_in, const int* in_sizes, int n_in,
                              void* d_out, int out_size, void* d_ws, size_t ws_size,
                              hipStream_t stream){
  PParams p;
  p.x = (const float*)d_in[0];
  for (int l = 0; l < 4; ++l){
    p.Wih[l] = (const float*)d_in[1 + 4*l + 0];
    p.Whh[l] = (const float*)d_in[1 + 4*l + 1];
    p.bih[l] = (const float*)d_in[1 + 4*l + 2];
    p.bhh[l] = (const float*)d_in[1 + 4*l + 3];
  }
  const float* Wo = (const float*)d_in[17];
  const float* bo = (const float*)d_in[18];

  const size_t FLAG_BYTES = (size_t)16 * 512 * 16;                // 128 KB
  const size_t SBYTES     = (size_t)512 * 64 * 512 * 2;           // 32 MB per full stream
  const size_t NEED       = FLAG_BYTES + 3 * SBYTES + (size_t)2 * 64 * 512 * 2;

  if (ws_size < NEED){
    zero_out_k<<<dim3(1), dim3(64), 0, stream>>>((float*)d_out, out_size);
    return;
  }

  char* ws = (char*)d_ws;
  p.flags = (unsigned char*)ws;
  size_t off = FLAG_BYTES;
  for (int l = 0; l < 3; ++l){ p.s[l] = (h16*)(ws + off); off += SBYTES; }
  p.s[3] = (h16*)(ws + off);

  hipMemsetAsync(p.flags, 0, FLAG_BYTES, stream);

  void* args[] = { &p };
  hipError_t e = hipLaunchCooperativeKernel((void*)lstm_persist, dim3(256), dim3(256),
                                            args, 0, stream);
  if (e != hipSuccess){
    // fallback: plain launch; 256 blocks @ 1 wg/CU co-reside on 256 CUs
    lstm_persist<<<dim3(256), dim3(256), 0, stream>>>(p);
  }

  // final timestep t=511 lives in s3 buffer (511 & 1) == 1
  head_k<<<dim3(64), dim3(64), 0, stream>>>(p.s[3] + (size_t)64 * 512, Wo, bo, (float*)d_out);
}